// Round 2
// baseline (257.779 us; speedup 1.0000x reference)
//
#include <hip/hip_runtime.h>
#include <hip/hip_bf16.h>
#include <stdint.h>

// Spiking ensemble update. S=16384. W=[S][S] f32 (1 GiB, the only heavy operand).
// lateral = spikes_f @ W  -> only rows with spike!=0 contribute (skip ~50% of W).
// Outputs (deduced round 1): flat FLOAT32, concat in return order:
//   [0:S) spikes(0/1), [S:2S) activation, [2S:3S) threshold, [3S:4S) freq.
// spikes input storage dtype unknown (bool) -> classified on device.

constexpr int S = 16384;
constexpr int TPB = 256;
constexpr int COLS_PER_BLOCK = TPB * 4;    // float4/thread -> 1024 cols per block
constexpr int MAX_CHUNKS = 64;

// ---------- spike dtype classification (reads only first 16384 bytes: safe for
// uint8/bool(16K), bf16(32K), int32/f32(64K) storage) ----------
// code: 0=int32, 1=uint8/bool, 2=f32, 3=bf16
__global__ void classify_spikes(const unsigned char* __restrict__ sp, int* __restrict__ code) {
  __shared__ int s3F_any, s3F_odd, sNZ_off;
  if (threadIdx.x == 0) { s3F_any = 0; s3F_odd = 0; sNZ_off = 0; }
  __syncthreads();
  for (int i = threadIdx.x; i < S; i += TPB) {
    unsigned char b = sp[i];
    if (b == 0x3F) {
      atomicOr(&s3F_any, 1);
      if ((i & 3) == 1) atomicOr(&s3F_odd, 1);   // bf16 1.0 high byte at odd offset
    }
    if (b != 0 && (i & 3) != 0) atomicOr(&sNZ_off, 1);
  }
  __syncthreads();
  if (threadIdx.x == 0) {
    int c;
    if (s3F_any)      c = s3F_odd ? 3 : 2;       // bf16 : f32
    else if (sNZ_off) c = 1;                     // uint8 bools
    else              c = 0;                     // int32 0/1
    *code = c;
  }
}

__global__ void extract_flags(const void* __restrict__ sp, const int* __restrict__ code,
                              unsigned char* __restrict__ flags) {
  int i = blockIdx.x * TPB + threadIdx.x;
  int c = *code;
  bool f;
  if (c == 0)      f = ((const int*)sp)[i] != 0;
  else if (c == 1) f = ((const unsigned char*)sp)[i] != 0;
  else if (c == 2) f = ((const float*)sp)[i] != 0.0f;
  else             f = ((const unsigned short*)sp)[i] != 0;
  flags[i] = f ? 1 : 0;
}

// ---------- main: partial lateral sums over row-chunks ----------
__global__ __launch_bounds__(TPB) void lateral_partial(
    const float* __restrict__ W, const unsigned char* __restrict__ flags,
    double* __restrict__ partial, int rpc) {
  const int r0 = blockIdx.y * rpc;
  const int nr = min(rpc, S - r0);
  const int col = blockIdx.x * COLS_PER_BLOCK + threadIdx.x * 4;
  double a0 = 0.0, a1 = 0.0, a2 = 0.0, a3 = 0.0;
  const float* Wp = W + (size_t)r0 * S + col;
  for (int i = 0; i < nr; ++i) {
    if (flags[r0 + i]) {   // wave-uniform: non-spiking rows never fetched from HBM
      float4 w = *reinterpret_cast<const float4*>(Wp);
      a0 += (double)w.x; a1 += (double)w.y; a2 += (double)w.z; a3 += (double)w.w;
    }
    Wp += S;
  }
  double* p = partial + (size_t)blockIdx.y * S + col;
  p[0] = a0; p[1] = a1; p[2] = a2; p[3] = a3;
}

// ---------- reduce + fused ensemble epilogue (f32 outputs) ----------
__device__ __forceinline__ void ensemble_epilogue(
    int j, float lateral,
    const float* __restrict__ x, const float* __restrict__ act,
    const float* __restrict__ thr, const float* __restrict__ freq,
    float* __restrict__ out) {
  float na = 0.9f * act[j] + x[j] + lateral;
  float t = thr[j];
  bool sp = na > t;
  float nf = 0.95f * freq[j] + 0.05f * (sp ? 1.0f : 0.0f);
  float nt = (nf > 0.2f) ? (t + 0.05f) : ((nf < 0.2f) ? (t / 1.05f) : t);
  if (sp) na = 0.0f;
  out[j]         = sp ? 1.0f : 0.0f;
  out[S + j]     = na;
  out[2 * S + j] = nt;
  out[3 * S + j] = nf;
}

__global__ __launch_bounds__(TPB) void ensemble_update(
    const double* __restrict__ partial, int n_chunks,
    const float* __restrict__ x, const float* __restrict__ act,
    const float* __restrict__ thr, const float* __restrict__ freq,
    float* __restrict__ out) {
  const int j = blockIdx.x * TPB + threadIdx.x;
  double lat = 0.0;
  for (int c = 0; c < n_chunks; ++c) lat += partial[(size_t)c * S + j];
  ensemble_epilogue(j, (float)lat, x, act, thr, freq, out);
}

// ---------- fallback if workspace is tiny: fused, assumes int32 spikes ----------
__global__ __launch_bounds__(TPB) void fused_full_int(
    const float* __restrict__ W, const int* __restrict__ spikes,
    const float* __restrict__ x, const float* __restrict__ act,
    const float* __restrict__ thr, const float* __restrict__ freq,
    float* __restrict__ out) {
  const int j = blockIdx.x * TPB + threadIdx.x;
  double lat = 0.0;
  for (int i = 0; i < S; ++i)
    if (spikes[i] != 0) lat += (double)W[(size_t)i * S + j];
  ensemble_epilogue(j, (float)lat, x, act, thr, freq, out);
}

extern "C" void kernel_launch(void* const* d_in, const int* in_sizes, int n_in,
                              void* d_out, int out_size, void* d_ws, size_t ws_size,
                              hipStream_t stream) {
  const float* x    = (const float*)d_in[0];
  const float* act  = (const float*)d_in[1];
  const float* thr  = (const float*)d_in[2];
  const float* freq = (const float*)d_in[3];
  const float* W    = (const float*)d_in[4];
  const void*  sp   = d_in[5];
  float* out = (float*)d_out;

  // ws layout: [0,4) dtype code | [64, 64+S) flags u8 | [32768, ...) partials f64
  const size_t PARTIAL_OFF = 32768;
  if (ws_size >= PARTIAL_OFF + (size_t)S * sizeof(double)) {
    int* code = (int*)d_ws;
    unsigned char* flags = (unsigned char*)d_ws + 64;
    double* partial = (double*)((char*)d_ws + PARTIAL_OFF);
    size_t avail_chunks = (ws_size - PARTIAL_OFF) / ((size_t)S * sizeof(double));
    int n_chunks = (int)(avail_chunks < (size_t)MAX_CHUNKS ? avail_chunks : (size_t)MAX_CHUNKS);
    int rpc = (S + n_chunks - 1) / n_chunks;

    classify_spikes<<<1, TPB, 0, stream>>>((const unsigned char*)sp, code);
    extract_flags<<<S / TPB, TPB, 0, stream>>>(sp, code, flags);
    dim3 g1(S / COLS_PER_BLOCK, n_chunks);
    lateral_partial<<<g1, TPB, 0, stream>>>(W, flags, partial, rpc);
    ensemble_update<<<S / TPB, TPB, 0, stream>>>(partial, n_chunks, x, act, thr, freq, out);
  } else {
    fused_full_int<<<S / TPB, TPB, 0, stream>>>(W, (const int*)sp, x, act, thr, freq, out);
  }
}

// Round 3
// 160.783 us; speedup vs baseline: 1.6033x; 1.6033x over previous
//
#include <hip/hip_runtime.h>
#include <hip/hip_bf16.h>
#include <stdint.h>

// Spiking ensemble update. S=16384. W=[S][S] f32 (1 GiB, the only heavy operand).
// lateral = spikes_f @ W -> only rows with spike!=0 contribute (~50% of W read).
// Outputs: flat FLOAT32 concat: [0:S) spikes, [S:2S) act, [2S:3S) thr, [3S:4S) freq.
// Round-2 lesson: branchy row-skip loop was latency-bound (2.1 TB/s eff).
// Round-3: compact spiking row indices, then unconditional 8-way-unrolled loads.

constexpr int S = 16384;
constexpr int TPB = 256;
constexpr int COLS_PER_BLOCK = TPB * 4;  // float4/thread -> 1024 cols per block
constexpr int N_CHUNKS = 128;            // rpc = 128 <= TPB (single-pass compaction)

// code: 0=int32, 1=uint8/bool, 2=f32, 3=bf16  (reads only first 16384 bytes: safe)
__global__ void classify_spikes(const unsigned char* __restrict__ sp, int* __restrict__ code) {
  __shared__ int s3F_any, s3F_odd, sNZ_off;
  if (threadIdx.x == 0) { s3F_any = 0; s3F_odd = 0; sNZ_off = 0; }
  __syncthreads();
  for (int i = threadIdx.x; i < S; i += TPB) {
    unsigned char b = sp[i];
    if (b == 0x3F) {
      atomicOr(&s3F_any, 1);
      if ((i & 3) == 1) atomicOr(&s3F_odd, 1);
    }
    if (b != 0 && (i & 3) != 0) atomicOr(&sNZ_off, 1);
  }
  __syncthreads();
  if (threadIdx.x == 0)
    *code = s3F_any ? (s3F_odd ? 3 : 2) : (sNZ_off ? 1 : 0);
}

__global__ void extract_flags(const void* __restrict__ sp, const int* __restrict__ code,
                              unsigned char* __restrict__ flags) {
  int i = blockIdx.x * TPB + threadIdx.x;
  int c = *code;
  bool f;
  if (c == 0)      f = ((const int*)sp)[i] != 0;
  else if (c == 1) f = ((const unsigned char*)sp)[i] != 0;
  else if (c == 2) f = ((const float*)sp)[i] != 0.0f;
  else             f = ((const unsigned short*)sp)[i] != 0;
  flags[i] = f ? 1 : 0;
}

// Deterministic per-chunk ordered compaction (ballot + wave prefix). rpc <= TPB.
__global__ __launch_bounds__(TPB) void compact_rows(
    const unsigned char* __restrict__ flags, int rpc,
    int* __restrict__ idx, int* __restrict__ counts) {
  const int b = blockIdx.x;
  const int r0 = b * rpc;
  const int tid = threadIdx.x;
  const int lane = tid & 63, wv = tid >> 6;
  __shared__ int woff[TPB / 64];
  bool f = (tid < rpc) && (flags[r0 + tid] != 0);
  unsigned long long m = __ballot(f);
  int within = __popcll(m & ((1ULL << lane) - 1ULL));
  if (lane == 0) woff[wv] = __popcll(m);
  __syncthreads();
  if (tid == 0) {
    int s = 0;
    for (int w = 0; w < TPB / 64; ++w) { int c = woff[w]; woff[w] = s; s += c; }
    counts[b] = s;
  }
  __syncthreads();
  if (f) idx[r0 + woff[wv] + within] = r0 + tid;
}

// Hot kernel: unconditional loads over compacted spiking rows, 8-deep MLP.
__global__ __launch_bounds__(TPB) void lateral_partial_idx(
    const float* __restrict__ W, const int* __restrict__ idx,
    const int* __restrict__ counts, int rpc, double* __restrict__ partial) {
  const int b = blockIdx.y;
  const int n = counts[b];
  const int* ids = idx + b * rpc;
  const int col = blockIdx.x * COLS_PER_BLOCK + threadIdx.x * 4;
  const float* Wc = W + col;
  double a0 = 0.0, a1 = 0.0, a2 = 0.0, a3 = 0.0;
  int i = 0;
  for (; i + 8 <= n; i += 8) {
    float4 w[8];
#pragma unroll
    for (int u = 0; u < 8; ++u)
      w[u] = *reinterpret_cast<const float4*>(Wc + (size_t)ids[i + u] * S);
#pragma unroll
    for (int u = 0; u < 8; ++u) {
      a0 += (double)w[u].x; a1 += (double)w[u].y;
      a2 += (double)w[u].z; a3 += (double)w[u].w;
    }
  }
  for (; i < n; ++i) {
    float4 w = *reinterpret_cast<const float4*>(Wc + (size_t)ids[i] * S);
    a0 += (double)w.x; a1 += (double)w.y; a2 += (double)w.z; a3 += (double)w.w;
  }
  double* p = partial + (size_t)b * S + col;
  p[0] = a0; p[1] = a1; p[2] = a2; p[3] = a3;
}

__device__ __forceinline__ void ensemble_epilogue(
    int j, float lateral,
    const float* __restrict__ x, const float* __restrict__ act,
    const float* __restrict__ thr, const float* __restrict__ freq,
    float* __restrict__ out) {
  float na = 0.9f * act[j] + x[j] + lateral;
  float t = thr[j];
  bool sp = na > t;
  float nf = 0.95f * freq[j] + 0.05f * (sp ? 1.0f : 0.0f);
  float nt = (nf > 0.2f) ? (t + 0.05f) : ((nf < 0.2f) ? (t / 1.05f) : t);
  if (sp) na = 0.0f;
  out[j]         = sp ? 1.0f : 0.0f;
  out[S + j]     = na;
  out[2 * S + j] = nt;
  out[3 * S + j] = nf;
}

__global__ __launch_bounds__(TPB) void ensemble_update(
    const double* __restrict__ partial, int n_chunks,
    const float* __restrict__ x, const float* __restrict__ act,
    const float* __restrict__ thr, const float* __restrict__ freq,
    float* __restrict__ out) {
  const int j = blockIdx.x * TPB + threadIdx.x;
  double lat = 0.0;
#pragma unroll 4
  for (int c = 0; c < n_chunks; ++c) lat += partial[(size_t)c * S + j];
  ensemble_epilogue(j, (float)lat, x, act, thr, freq, out);
}

// Fallbacks (ws too small) --------------------------------------------------
__global__ __launch_bounds__(TPB) void lateral_partial_branchy(
    const float* __restrict__ W, const unsigned char* __restrict__ flags,
    double* __restrict__ partial, int rpc) {
  const int r0 = blockIdx.y * rpc;
  const int nr = min(rpc, S - r0);
  const int col = blockIdx.x * COLS_PER_BLOCK + threadIdx.x * 4;
  double a0 = 0, a1 = 0, a2 = 0, a3 = 0;
  const float* Wp = W + (size_t)r0 * S + col;
  for (int i = 0; i < nr; ++i) {
    if (flags[r0 + i]) {
      float4 w = *reinterpret_cast<const float4*>(Wp);
      a0 += (double)w.x; a1 += (double)w.y; a2 += (double)w.z; a3 += (double)w.w;
    }
    Wp += S;
  }
  double* p = partial + (size_t)blockIdx.y * S + col;
  p[0] = a0; p[1] = a1; p[2] = a2; p[3] = a3;
}

__global__ __launch_bounds__(TPB) void fused_full_int(
    const float* __restrict__ W, const int* __restrict__ spikes,
    const float* __restrict__ x, const float* __restrict__ act,
    const float* __restrict__ thr, const float* __restrict__ freq,
    float* __restrict__ out) {
  const int j = blockIdx.x * TPB + threadIdx.x;
  double lat = 0.0;
  for (int i = 0; i < S; ++i)
    if (spikes[i] != 0) lat += (double)W[(size_t)i * S + j];
  ensemble_epilogue(j, (float)lat, x, act, thr, freq, out);
}

extern "C" void kernel_launch(void* const* d_in, const int* in_sizes, int n_in,
                              void* d_out, int out_size, void* d_ws, size_t ws_size,
                              hipStream_t stream) {
  const float* x    = (const float*)d_in[0];
  const float* act  = (const float*)d_in[1];
  const float* thr  = (const float*)d_in[2];
  const float* freq = (const float*)d_in[3];
  const float* W    = (const float*)d_in[4];
  const void*  sp   = d_in[5];
  float* out = (float*)d_out;

  // ws layout: code@0 | flags u8 @4096 (S) | idx i32 @20480 (S*4) |
  //            counts @86016 (512) | partial f64 @131072 (N_CHUNKS*S*8 = 16 MB)
  const size_t PART_OFF = 131072;
  const size_t need = PART_OFF + (size_t)N_CHUNKS * S * sizeof(double);

  if (ws_size >= need) {
    int* code            = (int*)d_ws;
    unsigned char* flags = (unsigned char*)d_ws + 4096;
    int* idx             = (int*)((char*)d_ws + 20480);
    int* counts          = (int*)((char*)d_ws + 86016);
    double* partial      = (double*)((char*)d_ws + PART_OFF);
    const int rpc = S / N_CHUNKS;  // 128

    classify_spikes<<<1, TPB, 0, stream>>>((const unsigned char*)sp, code);
    extract_flags<<<S / TPB, TPB, 0, stream>>>(sp, code, flags);
    compact_rows<<<N_CHUNKS, TPB, 0, stream>>>(flags, rpc, idx, counts);
    dim3 g1(S / COLS_PER_BLOCK, N_CHUNKS);
    lateral_partial_idx<<<g1, TPB, 0, stream>>>(W, idx, counts, rpc, partial);
    ensemble_update<<<S / TPB, TPB, 0, stream>>>(partial, N_CHUNKS, x, act, thr, freq, out);
  } else if (ws_size >= 32768 + (size_t)8 * S * sizeof(double)) {
    int* code            = (int*)d_ws;
    unsigned char* flags = (unsigned char*)d_ws + 64;
    double* partial      = (double*)((char*)d_ws + 32768);
    size_t avail = (ws_size - 32768) / ((size_t)S * sizeof(double));
    int n_chunks = (int)(avail < 64 ? avail : 64);
    int rpc = (S + n_chunks - 1) / n_chunks;
    classify_spikes<<<1, TPB, 0, stream>>>((const unsigned char*)sp, code);
    extract_flags<<<S / TPB, TPB, 0, stream>>>(sp, code, flags);
    dim3 g1(S / COLS_PER_BLOCK, n_chunks);
    lateral_partial_branchy<<<g1, TPB, 0, stream>>>(W, flags, partial, rpc);
    ensemble_update<<<S / TPB, TPB, 0, stream>>>(partial, n_chunks, x, act, thr, freq, out);
  } else {
    fused_full_int<<<S / TPB, TPB, 0, stream>>>(W, (const int*)sp, x, act, thr, freq, out);
  }
}

// Round 4
// 128.941 us; speedup vs baseline: 1.9992x; 1.2470x over previous
//
#include <hip/hip_runtime.h>
#include <hip/hip_bf16.h>
#include <stdint.h>

// Spiking ensemble update. S=16384. W=[S][S] f32 (1 GiB). lateral = spikes @ W:
// only spiking rows (~50%) are read -> ~537 MB floor @ 6.3 TB/s ~ 85 us.
// Outputs: flat f32 concat [spikes, activation, threshold, freq].
// R2: branchy skip loop latency-bound (2.1 TB/s). R3: compacted rows, 4KB
// slices -> 3.7 TB/s (DRAM stream efficiency). R4: 16KB contiguous slices,
// LDS-staged ids, nontemporal loads, fatter aux kernels.

constexpr int S = 16384;
constexpr int TPB = 256;
constexpr int N_CHUNKS = 256;     // rpc = 64 rows per chunk (one wave compacts it)
constexpr int RPC = 64;
constexpr int COL_BLOCKS = 4;     // 4096 cols = 16 KB contiguous per row visit
constexpr int COLW = S / COL_BLOCKS;

typedef float  f32x4 __attribute__((ext_vector_type(4)));
typedef double f64x4 __attribute__((ext_vector_type(4)));

// ---- spike dtype classification: 0=int32, 1=uint8/bool, 2=f32, 3=bf16 ----
// Reads first 16384 bytes (safe under all candidate widths).
__global__ void classify_spikes(const uint32_t* __restrict__ sp, int* __restrict__ code) {
  __shared__ int s3F_any, s3F_odd, sNZ_off;
  if (threadIdx.x == 0) { s3F_any = 0; s3F_odd = 0; sNZ_off = 0; }
  __syncthreads();
  int l3a = 0, l3o = 0, lnz = 0;
  for (int w = threadIdx.x; w < S / 4; w += TPB) {
    uint32_t v = sp[w];
#pragma unroll
    for (int b = 0; b < 4; ++b) {
      unsigned char byte = (v >> (8 * b)) & 0xFF;
      int i = w * 4 + b;
      if (byte == 0x3F) { l3a = 1; if ((i & 3) == 1) l3o = 1; }
      if (byte != 0 && (i & 3) != 0) lnz = 1;
    }
  }
  if (l3a) atomicOr(&s3F_any, 1);
  if (l3o) atomicOr(&s3F_odd, 1);
  if (lnz) atomicOr(&sNZ_off, 1);
  __syncthreads();
  if (threadIdx.x == 0)
    *code = s3F_any ? (s3F_odd ? 3 : 2) : (sNZ_off ? 1 : 0);
}

// ---- per-chunk ordered compaction, one wave per chunk ----
__global__ __launch_bounds__(64) void compact64(
    const void* __restrict__ sp, const int* __restrict__ code,
    int* __restrict__ idx, int* __restrict__ counts) {
  const int b = blockIdx.x, t = threadIdx.x;
  const int r = b * RPC + t;
  const int c = *code;
  bool f;
  if (c == 0)      f = ((const int*)sp)[r] != 0;
  else if (c == 1) f = ((const unsigned char*)sp)[r] != 0;
  else if (c == 2) f = ((const float*)sp)[r] != 0.0f;
  else             f = ((const unsigned short*)sp)[r] != 0;
  unsigned long long m = __ballot(f);
  int within = __popcll(m & ((1ULL << t) - 1ULL));
  if (f) idx[b * RPC + within] = r;
  if (t == 0) counts[b] = __popcll(m);
}

// ---- hot kernel: 16KB contiguous slice per spiking row, grid (4, 256) ----
__global__ __launch_bounds__(TPB) void lateral_partial_idx(
    const float* __restrict__ W, const int* __restrict__ idx,
    const int* __restrict__ counts, double* __restrict__ partial) {
  const int b = blockIdx.y;           // chunk
  const int q = blockIdx.x;           // column quarter
  const int n = counts[b];
  __shared__ int ids[RPC];
  if (threadIdx.x < RPC)
    ids[threadIdx.x] = (threadIdx.x < n) ? idx[b * RPC + threadIdx.x] : 0;
  __syncthreads();

  const float* Wc = W + q * COLW + threadIdx.x * 4;
  f64x4 a0 = 0.0, a1 = 0.0, a2 = 0.0, a3 = 0.0;
  int i = 0;
  for (; i + 2 <= n; i += 2) {
    const float* pa = Wc + (size_t)ids[i] * S;
    const float* pb = Wc + (size_t)ids[i + 1] * S;
    f32x4 wa0 = __builtin_nontemporal_load((const f32x4*)(pa));
    f32x4 wa1 = __builtin_nontemporal_load((const f32x4*)(pa + 1024));
    f32x4 wa2 = __builtin_nontemporal_load((const f32x4*)(pa + 2048));
    f32x4 wa3 = __builtin_nontemporal_load((const f32x4*)(pa + 3072));
    f32x4 wb0 = __builtin_nontemporal_load((const f32x4*)(pb));
    f32x4 wb1 = __builtin_nontemporal_load((const f32x4*)(pb + 1024));
    f32x4 wb2 = __builtin_nontemporal_load((const f32x4*)(pb + 2048));
    f32x4 wb3 = __builtin_nontemporal_load((const f32x4*)(pb + 3072));
    a0 += __builtin_convertvector(wa0, f64x4) + __builtin_convertvector(wb0, f64x4);
    a1 += __builtin_convertvector(wa1, f64x4) + __builtin_convertvector(wb1, f64x4);
    a2 += __builtin_convertvector(wa2, f64x4) + __builtin_convertvector(wb2, f64x4);
    a3 += __builtin_convertvector(wa3, f64x4) + __builtin_convertvector(wb3, f64x4);
  }
  if (i < n) {
    const float* pa = Wc + (size_t)ids[i] * S;
    a0 += __builtin_convertvector(__builtin_nontemporal_load((const f32x4*)(pa)), f64x4);
    a1 += __builtin_convertvector(__builtin_nontemporal_load((const f32x4*)(pa + 1024)), f64x4);
    a2 += __builtin_convertvector(__builtin_nontemporal_load((const f32x4*)(pa + 2048)), f64x4);
    a3 += __builtin_convertvector(__builtin_nontemporal_load((const f32x4*)(pa + 3072)), f64x4);
  }
  double* dst = partial + (size_t)b * S + q * COLW + threadIdx.x * 4;
  *(f64x4*)(dst)        = a0;
  *(f64x4*)(dst + 1024) = a1;
  *(f64x4*)(dst + 2048) = a2;
  *(f64x4*)(dst + 3072) = a3;
}

// ---- reduce 256 partials + fused epilogue ----
__device__ __forceinline__ void ensemble_epilogue(
    int j, float lateral,
    const float* __restrict__ x, const float* __restrict__ act,
    const float* __restrict__ thr, const float* __restrict__ freq,
    float* __restrict__ out) {
  float na = 0.9f * act[j] + x[j] + lateral;
  float t = thr[j];
  bool sp = na > t;
  float nf = 0.95f * freq[j] + 0.05f * (sp ? 1.0f : 0.0f);
  float nt = (nf > 0.2f) ? (t + 0.05f) : ((nf < 0.2f) ? (t / 1.05f) : t);
  if (sp) na = 0.0f;
  out[j]         = sp ? 1.0f : 0.0f;
  out[S + j]     = na;
  out[2 * S + j] = nt;
  out[3 * S + j] = nf;
}

__global__ __launch_bounds__(TPB) void ensemble_update(
    const double* __restrict__ partial,
    const float* __restrict__ x, const float* __restrict__ act,
    const float* __restrict__ thr, const float* __restrict__ freq,
    float* __restrict__ out) {
  const int j = blockIdx.x * TPB + threadIdx.x;
  double l0 = 0.0, l1 = 0.0, l2 = 0.0, l3 = 0.0;
#pragma unroll 4
  for (int c = 0; c < N_CHUNKS; c += 4) {
    l0 += partial[(size_t)c * S + j];
    l1 += partial[(size_t)(c + 1) * S + j];
    l2 += partial[(size_t)(c + 2) * S + j];
    l3 += partial[(size_t)(c + 3) * S + j];
  }
  ensemble_epilogue(j, (float)((l0 + l1) + (l2 + l3)), x, act, thr, freq, out);
}

// ---- minimal fallback (ws too small; assumes int32 spikes) ----
__global__ __launch_bounds__(TPB) void fused_full_int(
    const float* __restrict__ W, const int* __restrict__ spikes,
    const float* __restrict__ x, const float* __restrict__ act,
    const float* __restrict__ thr, const float* __restrict__ freq,
    float* __restrict__ out) {
  const int j = blockIdx.x * TPB + threadIdx.x;
  double lat = 0.0;
  for (int i = 0; i < S; ++i)
    if (spikes[i] != 0) lat += (double)W[(size_t)i * S + j];
  ensemble_epilogue(j, (float)lat, x, act, thr, freq, out);
}

extern "C" void kernel_launch(void* const* d_in, const int* in_sizes, int n_in,
                              void* d_out, int out_size, void* d_ws, size_t ws_size,
                              hipStream_t stream) {
  const float* x    = (const float*)d_in[0];
  const float* act  = (const float*)d_in[1];
  const float* thr  = (const float*)d_in[2];
  const float* freq = (const float*)d_in[3];
  const float* W    = (const float*)d_in[4];
  const void*  sp   = d_in[5];
  float* out = (float*)d_out;

  // ws: code@0 | idx i32 @4096 (S*4=64K) | counts @69632 (1K) | partial f64 @1M (32M)
  const size_t PART_OFF = 1 << 20;
  const size_t need = PART_OFF + (size_t)N_CHUNKS * S * sizeof(double);

  if (ws_size >= need) {
    int* code       = (int*)d_ws;
    int* idx        = (int*)((char*)d_ws + 4096);
    int* counts     = (int*)((char*)d_ws + 69632);
    double* partial = (double*)((char*)d_ws + PART_OFF);

    classify_spikes<<<1, TPB, 0, stream>>>((const uint32_t*)sp, code);
    compact64<<<N_CHUNKS, 64, 0, stream>>>(sp, code, idx, counts);
    dim3 g1(COL_BLOCKS, N_CHUNKS);
    lateral_partial_idx<<<g1, TPB, 0, stream>>>(W, idx, counts, partial);
    ensemble_update<<<S / TPB, TPB, 0, stream>>>(partial, x, act, thr, freq, out);
  } else {
    fused_full_int<<<S / TPB, TPB, 0, stream>>>(W, (const int*)sp, x, act, thr, freq, out);
  }
}